// Round 12
// baseline (526.741 us; speedup 1.0000x reference)
//
#include <hip/hip_runtime.h>

#define NN 50000
#define NE 800000
#define RR 8
#define BB 8
#define EPSV 1e-5f
#define SCAN_B ((NN + 255) / 256)   // 196
#define NGRP 64

typedef unsigned short bfu;
typedef signed char i8;
typedef __attribute__((ext_vector_type(8))) short bf16x8;
typedef __attribute__((ext_vector_type(4))) float f32x4;

__device__ inline float bf2f(bfu u) { return __uint_as_float(((unsigned)u) << 16); }
__device__ inline bfu f2bf(float f) {
    unsigned u = __float_as_uint(f);
    return (bfu)((u + 0x7fffu + ((u >> 16) & 1u)) >> 16);   // RTNE
}

#define NW1 36864L
#define NW2 36864L
#define NW3 18432L
#define NZ  (400000L + 50000L + 2L * NGRP * 128 + 256)

// ---------------- W packing: logical W[k][o] -> MFMA B-frag layout ----------------
__device__ inline void build_one(const float* __restrict__ comp, const float* __restrict__ bases,
                                 const float* __restrict__ root, bfu* __restrict__ Wp,
                                 int O, int idx) {
    int k = idx / O, o = idx % O;
    float val;
    if (k < 512) {
        int r = k >> 6, i = k & 63;
        val = 0.f;
#pragma unroll
        for (int b = 0; b < BB; ++b)
            val += comp[r * BB + b] * bases[(b * 64 + i) * O + o];
    } else {
        val = root[(k - 512) * O + o];
    }
    int kt = k >> 5, kk = k & 31;
    int lane = ((kk >> 3) << 4) | (o & 15);
    int pos = ((kt * (O / 16) + (o >> 4)) * 64 + lane) * 8 + (kk & 7);
    Wp[pos] = f2bf(val);
}

// ---------------- once: W builds + zero (cnt|fill|stats1|stats2|dhist) ----------------
__global__ void prep(const float* __restrict__ c1, const float* __restrict__ b1,
                     const float* __restrict__ r1, bfu* __restrict__ Wp1,
                     const float* __restrict__ c2, const float* __restrict__ b2,
                     const float* __restrict__ r2, bfu* __restrict__ Wp2,
                     const float* __restrict__ c3, const float* __restrict__ b3,
                     const float* __restrict__ r3, bfu* __restrict__ Wp3,
                     float* __restrict__ zbase) {
    long i = (long)blockIdx.x * blockDim.x + threadIdx.x;
    long stride = (long)gridDim.x * blockDim.x;
    const long tot = NW1 + NW2 + NW3 + NZ;
    for (; i < tot; i += stride) {
        if (i < NW1) build_one(c1, b1, r1, Wp1, 64, (int)i);
        else if (i < NW1 + NW2) build_one(c2, b2, r2, Wp2, 64, (int)(i - NW1));
        else if (i < NW1 + NW2 + NW3) build_one(c3, b3, r3, Wp3, 32, (int)(i - NW1 - NW2));
        else zbase[i - (NW1 + NW2 + NW3)] = 0.f;
    }
}

// ---------------- once: x -> xb (bf16) + x8 (int8 row-scaled) + xs (row scale) ----------------
__global__ __launch_bounds__(256) void cvt_rows(const float* __restrict__ x,
                                                bfu* __restrict__ xb,
                                                i8* __restrict__ x8,
                                                float* __restrict__ xs) {
    int wv = threadIdx.x >> 6, lane = threadIdx.x & 63;
    int gw = blockIdx.x * 4 + wv, nw = gridDim.x * 4;
    for (int n = gw; n < NN; n += nw) {
        float v = x[(size_t)n * 64 + lane];
        xb[(size_t)n * 64 + lane] = f2bf(v);
        float am = fabsf(v);
#pragma unroll
        for (int d = 1; d < 64; d <<= 1) am = fmaxf(am, __shfl_xor(am, d));
        am = fmaxf(am, 1e-20f);
        float inv = 127.f / am;
        x8[(size_t)n * 64 + lane] = (i8)__float2int_rn(v * inv);
        if (lane == 0) xs[n] = am * (1.f / 127.f);
    }
}

// ---------------- once: per-(dst,rel) counts, range-binned (4 ranges) ----------------
__global__ void edge_count(const int* __restrict__ ei, const int* __restrict__ et,
                           float* __restrict__ cnt) {
    int range = blockIdx.x >> 8;
    int lo = range * (NN / 4), hi = lo + NN / 4;
    int i = (blockIdx.x & 255) * 256 + threadIdx.x;
    for (int e = i; e < NE; e += 256 * 256) {
        int d = ei[NE + e];
        if (d >= lo && d < hi)
            atomicAdd(&cnt[(size_t)d * RR + et[e]], 1.0f);
    }
}

// ---------------- once: exclusive scan of degree -> offs ----------------
__global__ void scan1(const float* __restrict__ cnt, int* __restrict__ offs, int* __restrict__ bsum) {
    __shared__ int sh[256];
    int b = blockIdx.x, t = threadIdx.x;
    int i = b * 256 + t;
    int v = 0;
    if (i < NN) {
        float s = 0.f;
#pragma unroll
        for (int r = 0; r < RR; ++r) s += cnt[(size_t)i * RR + r];
        v = (int)s;
    }
    sh[t] = v;
    __syncthreads();
    for (int s = 1; s < 256; s <<= 1) {
        int tmp = (t >= s) ? sh[t - s] : 0;
        __syncthreads();
        sh[t] += tmp;
        __syncthreads();
    }
    if (i < NN) offs[i] = sh[t] - v;
    if (t == 255) bsum[b] = sh[255];
}

__global__ void scan2(int* __restrict__ bsum, int* __restrict__ offs) {
    if (threadIdx.x == 0 && blockIdx.x == 0) {
        int run = 0;
        for (int b = 0; b < SCAN_B; ++b) { int t = bsum[b]; bsum[b] = run; run += t; }
        offs[NN] = run;
    }
}

__global__ void scan3(int* __restrict__ offs, const int* __restrict__ bsum) {
    int b = blockIdx.x, t = threadIdx.x;
    int i = b * 256 + t;
    if (i < NN) offs[i] += bsum[b];
}

// ---------------- once: place edges dst-sorted, range-binned (4 ranges) ----------------
__global__ void place(const int* __restrict__ ei, const int* __restrict__ et,
                      const int* __restrict__ offs, int* __restrict__ fill,
                      unsigned* __restrict__ esrt) {
    int range = blockIdx.x >> 8;
    int lo = range * (NN / 4), hi = lo + NN / 4;
    int i = (blockIdx.x & 255) * 256 + threadIdx.x;
    for (int e = i; e < NE; e += 256 * 256) {
        int d = ei[NE + e];
        if (d >= lo && d < hi) {
            int pos = offs[d] + atomicAdd(&fill[d], 1);
            esrt[pos] = ((unsigned)ei[e] << 3) | (unsigned)et[e];
        }
    }
}

// ---------------- once: counting sort of nodes by descending clamped degree ----------------
__global__ void dhist(const int* __restrict__ offs, int* __restrict__ hist) {
    int i = blockIdx.x * blockDim.x + threadIdx.x;
    if (i < NN) {
        int d = offs[i + 1] - offs[i]; if (d > 255) d = 255;
        atomicAdd(&hist[255 - d], 1);
    }
}
__global__ void dscan(int* __restrict__ hist) {   // 1 block x 256: in-place exclusive scan
    __shared__ int sh[256];
    int t = threadIdx.x;
    int v = hist[t]; sh[t] = v; __syncthreads();
    for (int s = 1; s < 256; s <<= 1) {
        int tmp = (t >= s) ? sh[t - s] : 0;
        __syncthreads();
        sh[t] += tmp;
        __syncthreads();
    }
    hist[t] = sh[t] - v;
}
__global__ void dplace(const int* __restrict__ offs, int* __restrict__ hist, int* __restrict__ perm) {
    int i = blockIdx.x * blockDim.x + threadIdx.x;
    if (i < NN) {
        int d = offs[i + 1] - offs[i]; if (d > 255) d = 255;
        int slot = atomicAdd(&hist[255 - d], 1);
        perm[slot] = i;
    }
}

// ---------------- fused per layer: aggregate(int8) -> LDS A-frags -> MFMA GEMM (+BN stats) ----------------
#define ACCUMS(SU, V)                          \
    switch ((SU) & 7) {                        \
        case 0: a0 += (V); break;              \
        case 1: a1 += (V); break;              \
        case 2: a2 += (V); break;              \
        case 3: a3 += (V); break;              \
        case 4: a4 += (V); break;              \
        case 5: a5 += (V); break;              \
        case 6: a6 += (V); break;              \
        default: a7 += (V); break;             \
    }
#define RDL(X, L) __builtin_amdgcn_readlane((int)(X), (L))

// 1024 threads = 16 waves; ONE (degree-matched) node per wave; GEMM by waves 0..CT-1.
template <int O, bool RELU, bool STATS>
__global__ __launch_bounds__(1024, 8) void agg_gemm(const int* __restrict__ perm,
                                                    const int* __restrict__ offs,
                                                    const unsigned* __restrict__ esrt,
                                                    const float* __restrict__ cnt,
                                                    const i8* __restrict__ x8,
                                                    const float* __restrict__ xs,
                                                    const bfu* __restrict__ xb,
                                                    const bfu* __restrict__ Wp,
                                                    const float* __restrict__ bias,
                                                    float* __restrict__ outp,
                                                    float* __restrict__ stats) {
    constexpr int CT = O / 16;
    __shared__ bfu Af[1152 * 8];                     // 18 k-tiles x 64 lanes x 8 bf16 = 18KB
    __shared__ int permLds[16];
    int wave = threadIdx.x >> 6, lane = threadIdx.x & 63;
    int n0 = blockIdx.x * 16;
    int row = wave;                                   // one node per wave
    int n = perm[n0 + row];                           // degree-matched within block
    if (lane == 0) permLds[row] = n;
    int c = lane;
    int swz_lo = ((c >> 3) & 3) << 4;

    int j0 = offs[n], j1 = offs[n + 1];
    float a0 = 0.f, a1 = 0.f, a2 = 0.f, a3 = 0.f, a4 = 0.f, a5 = 0.f, a6 = 0.f, a7 = 0.f;
    int j = j0;
    unsigned mye = 0;
    if (j + 8 <= j1) mye = esrt[j + (lane & 7)];      // prefetch batch 0
    for (; j + 8 <= j1;) {
        unsigned cur = mye;
        float sc8 = xs[cur >> 3];                     // lanes 0-7 carry the 8 scales
        int jn = j + 8;
        if (jn + 8 <= j1) mye = esrt[jn + (lane & 7)];// prefetch next batch
        int scb = __float_as_int(sc8);
        int s0 = RDL(cur, 0), s1 = RDL(cur, 1), s2 = RDL(cur, 2), s3 = RDL(cur, 3);
        int s4 = RDL(cur, 4), s5 = RDL(cur, 5), s6 = RDL(cur, 6), s7 = RDL(cur, 7);
        float q0 = (float)x8[(size_t)((unsigned)s0 >> 3) * 64 + lane];
        float q1 = (float)x8[(size_t)((unsigned)s1 >> 3) * 64 + lane];
        float q2 = (float)x8[(size_t)((unsigned)s2 >> 3) * 64 + lane];
        float q3 = (float)x8[(size_t)((unsigned)s3 >> 3) * 64 + lane];
        float q4 = (float)x8[(size_t)((unsigned)s4 >> 3) * 64 + lane];
        float q5 = (float)x8[(size_t)((unsigned)s5 >> 3) * 64 + lane];
        float q6 = (float)x8[(size_t)((unsigned)s6 >> 3) * 64 + lane];
        float q7 = (float)x8[(size_t)((unsigned)s7 >> 3) * 64 + lane];
        float c0 = __int_as_float(RDL(scb, 0)), c1 = __int_as_float(RDL(scb, 1));
        float c2 = __int_as_float(RDL(scb, 2)), c3 = __int_as_float(RDL(scb, 3));
        float c4 = __int_as_float(RDL(scb, 4)), c5 = __int_as_float(RDL(scb, 5));
        float c6 = __int_as_float(RDL(scb, 6)), c7 = __int_as_float(RDL(scb, 7));
        ACCUMS(s0, q0 * c0) ACCUMS(s1, q1 * c1) ACCUMS(s2, q2 * c2) ACCUMS(s3, q3 * c3)
        ACCUMS(s4, q4 * c4) ACCUMS(s5, q5 * c5) ACCUMS(s6, q6 * c6) ACCUMS(s7, q7 * c7)
        j = jn;
    }
    if (j + 4 <= j1) {
        unsigned m4 = esrt[j + (lane & 3)];
        float sc4 = xs[m4 >> 3];
        int scb = __float_as_int(sc4);
        int s0 = RDL(m4, 0), s1 = RDL(m4, 1), s2 = RDL(m4, 2), s3 = RDL(m4, 3);
        float q0 = (float)x8[(size_t)((unsigned)s0 >> 3) * 64 + lane];
        float q1 = (float)x8[(size_t)((unsigned)s1 >> 3) * 64 + lane];
        float q2 = (float)x8[(size_t)((unsigned)s2 >> 3) * 64 + lane];
        float q3 = (float)x8[(size_t)((unsigned)s3 >> 3) * 64 + lane];
        float c0 = __int_as_float(RDL(scb, 0)), c1 = __int_as_float(RDL(scb, 1));
        float c2 = __int_as_float(RDL(scb, 2)), c3 = __int_as_float(RDL(scb, 3));
        ACCUMS(s0, q0 * c0) ACCUMS(s1, q1 * c1) ACCUMS(s2, q2 * c2) ACCUMS(s3, q3 * c3)
        j += 4;
    }
    for (; j < j1; ++j) {
        int s0 = __builtin_amdgcn_readfirstlane((int)esrt[j]);
        float q0 = (float)x8[(size_t)((unsigned)s0 >> 3) * 64 + lane];
        float c0 = xs[(unsigned)s0 >> 3];
        ACCUMS(s0, q0 * c0)
    }
    // normalize + write A-fragments (granule-XOR-swizzled; verified rounds 7-11)
#define WR(r, ar) {                                                            \
    float inv = 1.f / fmaxf(cnt[(size_t)n * RR + (r)], 1.f);                   \
    bfu bv = f2bf((ar) * inv);                                                 \
    int g = (2 * (r) + (c >> 5)) * 64 + (row | swz_lo);                        \
    int gs = g ^ ((g >> 3) & 7) ^ ((g >> 6) & 7);                              \
    Af[gs * 8 + (c & 7)] = bv; }
    WR(0, a0) WR(1, a1) WR(2, a2) WR(3, a3)
    WR(4, a4) WR(5, a5) WR(6, a6) WR(7, a7)
#undef WR
    {   // root-input columns k=512+c (kt = 16,17), full bf16 precision
        bfu bv = xb[(size_t)n * 64 + lane];
        int g = (16 + (c >> 5)) * 64 + (row | swz_lo);
        int gs = g ^ ((g >> 3) & 7) ^ ((g >> 6) & 7);
        Af[gs * 8 + (c & 7)] = bv;
    }
    __syncthreads();

    int ct = wave;
    if (ct < CT) {                                    // remaining waves retire early
        f32x4 acc = (f32x4){0.f, 0.f, 0.f, 0.f};
#pragma unroll
        for (int kt = 0; kt < 18; ++kt) {
            int g = kt * 64 + lane;
            int gs = g ^ ((g >> 3) & 7) ^ ((g >> 6) & 7);
            bf16x8 af = *(const bf16x8*)&Af[gs * 8];
            bf16x8 bfv = *(const bf16x8*)&Wp[((size_t)(kt * CT + ct) * 64 + lane) * 8];
            acc = __builtin_amdgcn_mfma_f32_16x16x32_bf16(af, bfv, acc, 0, 0, 0);
        }
        int col = ct * 16 + (lane & 15);
        float b = bias[col];
        float ssum = 0.f, sq = 0.f;
#pragma unroll
        for (int jj = 0; jj < 4; ++jj) {
            int orow = (lane >> 4) * 4 + jj;
            int pn = permLds[orow];
            float v = acc[jj] + b;
            if (RELU) v = fmaxf(v, 0.f);
            outp[(size_t)pn * O + col] = v;
            if (STATS) { ssum += v; sq += v * v; }
        }
        if (STATS) {
            ssum += __shfl_xor(ssum, 16); ssum += __shfl_xor(ssum, 32);
            sq   += __shfl_xor(sq, 16);   sq   += __shfl_xor(sq, 32);
            if ((lane >> 4) == 0) {
                int g = blockIdx.x & (NGRP - 1);
                atomicAdd(&stats[g * 128 + col], ssum);
                atomicAdd(&stats[g * 128 + 64 + col], sq);
            }
        }
    }
}

// ---------------- BN: finalize + apply; emits bf16 + row-scaled int8 ----------------
template <bool HASRES>
__global__ __launch_bounds__(256) void bn_apply(const float* __restrict__ y,
                                                const float* __restrict__ stats,
                                                const float* __restrict__ gamma,
                                                const float* __restrict__ beta,
                                                const bfu* __restrict__ resb,
                                                bfu* __restrict__ hb,
                                                i8* __restrict__ h8,
                                                float* __restrict__ hs) {
    __shared__ float sc[128];
    int t = threadIdx.x;
    if (t < 64) {
        float s = 0.f, q = 0.f;
        for (int g = 0; g < NGRP; ++g) {
            s += stats[g * 128 + t];
            q += stats[g * 128 + 64 + t];
        }
        float mu = s / (float)NN;
        float var = q / (float)NN - mu * mu;
        float scale = gamma[t] * rsqrtf(var + EPSV);
        sc[t] = scale;
        sc[64 + t] = beta[t] - mu * scale;
    }
    __syncthreads();
    int wv = threadIdx.x >> 6, lane = threadIdx.x & 63;
    int gw = blockIdx.x * 4 + wv, nw = gridDim.x * 4;
    for (int n = gw; n < NN; n += nw) {
        float v = y[(size_t)n * 64 + lane] * sc[lane] + sc[64 + lane];
        if (HASRES) v += bf2f(resb[(size_t)n * 64 + lane]);
        hb[(size_t)n * 64 + lane] = f2bf(v);
        float am = fabsf(v);
#pragma unroll
        for (int d = 1; d < 64; d <<= 1) am = fmaxf(am, __shfl_xor(am, d));
        am = fmaxf(am, 1e-20f);
        float inv = 127.f / am;
        h8[(size_t)n * 64 + lane] = (i8)__float2int_rn(v * inv);
        if (lane == 0) hs[n] = am * (1.f / 127.f);
    }
}

extern "C" void kernel_launch(void* const* d_in, const int* in_sizes, int n_in,
                              void* d_out, int out_size, void* d_ws, size_t ws_size,
                              hipStream_t stream) {
    const float* x      = (const float*)d_in[0];
    const int*   ei     = (const int*)d_in[1];
    const int*   et     = (const int*)d_in[2];
    const float* comp1  = (const float*)d_in[3];
    const float* bases1 = (const float*)d_in[4];
    const float* root1  = (const float*)d_in[5];
    const float* bias1  = (const float*)d_in[6];
    const float* comp2  = (const float*)d_in[7];
    const float* bases2 = (const float*)d_in[8];
    const float* root2  = (const float*)d_in[9];
    const float* bias2  = (const float*)d_in[10];
    const float* comp3  = (const float*)d_in[11];
    const float* bases3 = (const float*)d_in[12];
    const float* root3  = (const float*)d_in[13];
    const float* bias3  = (const float*)d_in[14];
    const float* gamma1 = (const float*)d_in[15];
    const float* beta1  = (const float*)d_in[16];
    const float* gamma2 = (const float*)d_in[17];
    const float* beta2  = (const float*)d_in[18];
    float* out = (float*)d_out;

    float* ws = (float*)d_ws;
    size_t off = 0;
    bfu* Wp1 = (bfu*)(ws + off); off += 18432;                // 36864 bf16
    bfu* Wp2 = (bfu*)(ws + off); off += 18432;
    bfu* Wp3 = (bfu*)(ws + off); off += 9216;                 // 18432 bf16
    float* cnt    = ws + off; off += (size_t)NN * RR;         // -- zero region start
    int*   fill   = (int*)(ws + off); off += NN;
    float* stats1 = ws + off; off += NGRP * 128;
    float* stats2 = ws + off; off += NGRP * 128;
    int*   hist   = (int*)(ws + off); off += 256;             // -- zero region end
    float* y  = ws + off; off += (size_t)NN * 64;
    bfu* xb   = (bfu*)(ws + off); off += (size_t)NN * 32;
    bfu* h1b  = (bfu*)(ws + off); off += (size_t)NN * 32;
    bfu* hb   = (bfu*)(ws + off); off += (size_t)NN * 32;
    i8*  x8   = (i8*)(ws + off);  off += (size_t)NN * 16;
    i8*  h1_8 = (i8*)(ws + off);  off += (size_t)NN * 16;
    i8*  h_8  = (i8*)(ws + off);  off += (size_t)NN * 16;
    float* xsc  = ws + off; off += NN;
    float* h1sc = ws + off; off += NN;
    float* hsc  = ws + off; off += NN;
    int* offs = (int*)(ws + off); off += NN + 4;
    int* bsum = (int*)(ws + off); off += 256;
    int* perm = (int*)(ws + off); off += NN;
    unsigned* esrt = (unsigned*)(ws + off); off += NE;

    // ---- once: prep (W pack + zeros), cvt, counts, CSR, degree-sort ----
    prep<<<dim3(1024), dim3(256), 0, stream>>>(comp1, bases1, root1, Wp1,
                                               comp2, bases2, root2, Wp2,
                                               comp3, bases3, root3, Wp3, cnt);
    cvt_rows<<<dim3(512), dim3(256), 0, stream>>>(x, xb, x8, xsc);
    edge_count<<<dim3(1024), dim3(256), 0, stream>>>(ei, et, cnt);
    scan1<<<dim3(SCAN_B), dim3(256), 0, stream>>>(cnt, offs, bsum);
    scan2<<<dim3(1), dim3(64), 0, stream>>>(bsum, offs);
    scan3<<<dim3(SCAN_B), dim3(256), 0, stream>>>(offs, bsum);
    place<<<dim3(1024), dim3(256), 0, stream>>>(ei, et, offs, fill, esrt);
    dhist<<<dim3(SCAN_B), dim3(256), 0, stream>>>(offs, hist);
    dscan<<<dim3(1), dim3(256), 0, stream>>>(hist);
    dplace<<<dim3(SCAN_B), dim3(256), 0, stream>>>(offs, hist, perm);

    // ---- layer 1 ----
    agg_gemm<64, true, true><<<dim3(NN / 16), dim3(1024), 0, stream>>>(perm, offs, esrt, cnt, x8, xsc, xb, Wp1, bias1, y, stats1);
    bn_apply<false><<<dim3(1024), dim3(256), 0, stream>>>(y, stats1, gamma1, beta1, nullptr, h1b, h1_8, h1sc);

    // ---- layer 2 ----
    agg_gemm<64, true, true><<<dim3(NN / 16), dim3(1024), 0, stream>>>(perm, offs, esrt, cnt, h1_8, h1sc, h1b, Wp2, bias2, y, stats2);
    bn_apply<true><<<dim3(1024), dim3(256), 0, stream>>>(y, stats2, gamma2, beta2, h1b, hb, h_8, hsc);

    // ---- layer 3 (output) ----
    agg_gemm<32, false, false><<<dim3(NN / 16), dim3(1024), 0, stream>>>(perm, offs, esrt, cnt, h_8, hsc, hb, Wp3, bias3, out, nullptr);
}

// Round 13
// 395.672 us; speedup vs baseline: 1.3313x; 1.3313x over previous
//
#include <hip/hip_runtime.h>

#define NN 50000
#define NE 800000
#define RR 8
#define BB 8
#define EPSV 1e-5f
#define SCAN_B ((NN + 255) / 256)   // 196
#define NGRP 64

typedef unsigned short bfu;
typedef signed char i8;
typedef __attribute__((ext_vector_type(8))) short bf16x8;
typedef __attribute__((ext_vector_type(4))) float f32x4;

__device__ inline float bf2f(bfu u) { return __uint_as_float(((unsigned)u) << 16); }
__device__ inline bfu f2bf(float f) {
    unsigned u = __float_as_uint(f);
    return (bfu)((u + 0x7fffu + ((u >> 16) & 1u)) >> 16);   // RTNE
}

#define NW1 36864L
#define NW2 36864L
#define NW3 18432L
// zero region: cnt (NN*8 f32) + fill2 (NN*8 i32) + stats1 + stats2
#define NZ  (400000L + 400000L + 2L * NGRP * 128)

// ---------------- W packing: logical W[k][o] -> MFMA B-frag layout ----------------
__device__ inline void build_one(const float* __restrict__ comp, const float* __restrict__ bases,
                                 const float* __restrict__ root, bfu* __restrict__ Wp,
                                 int O, int idx) {
    int k = idx / O, o = idx % O;
    float val;
    if (k < 512) {
        int r = k >> 6, i = k & 63;
        val = 0.f;
#pragma unroll
        for (int b = 0; b < BB; ++b)
            val += comp[r * BB + b] * bases[(b * 64 + i) * O + o];
    } else {
        val = root[(k - 512) * O + o];
    }
    int kt = k >> 5, kk = k & 31;
    int lane = ((kk >> 3) << 4) | (o & 15);
    int pos = ((kt * (O / 16) + (o >> 4)) * 64 + lane) * 8 + (kk & 7);
    Wp[pos] = f2bf(val);
}

// ---------------- once: W builds + zero (cnt|fill2|stats1|stats2) ----------------
__global__ void prep(const float* __restrict__ c1, const float* __restrict__ b1,
                     const float* __restrict__ r1, bfu* __restrict__ Wp1,
                     const float* __restrict__ c2, const float* __restrict__ b2,
                     const float* __restrict__ r2, bfu* __restrict__ Wp2,
                     const float* __restrict__ c3, const float* __restrict__ b3,
                     const float* __restrict__ r3, bfu* __restrict__ Wp3,
                     float* __restrict__ zbase) {
    long i = (long)blockIdx.x * blockDim.x + threadIdx.x;
    long stride = (long)gridDim.x * blockDim.x;
    const long tot = NW1 + NW2 + NW3 + NZ;
    for (; i < tot; i += stride) {
        if (i < NW1) build_one(c1, b1, r1, Wp1, 64, (int)i);
        else if (i < NW1 + NW2) build_one(c2, b2, r2, Wp2, 64, (int)(i - NW1));
        else if (i < NW1 + NW2 + NW3) build_one(c3, b3, r3, Wp3, 32, (int)(i - NW1 - NW2));
        else zbase[i - (NW1 + NW2 + NW3)] = 0.f;
    }
}

// ---------------- once: x -> xb (bf16) + x8 (int8 row-scaled) + xs (row scale) ----------------
__global__ __launch_bounds__(256) void cvt_rows(const float* __restrict__ x,
                                                bfu* __restrict__ xb,
                                                i8* __restrict__ x8,
                                                float* __restrict__ xs) {
    int wv = threadIdx.x >> 6, lane = threadIdx.x & 63;
    int gw = blockIdx.x * 4 + wv, nw = gridDim.x * 4;
    for (int n = gw; n < NN; n += nw) {
        float v = x[(size_t)n * 64 + lane];
        xb[(size_t)n * 64 + lane] = f2bf(v);
        float am = fabsf(v);
#pragma unroll
        for (int d = 1; d < 64; d <<= 1) am = fmaxf(am, __shfl_xor(am, d));
        am = fmaxf(am, 1e-20f);
        float inv = 127.f / am;
        x8[(size_t)n * 64 + lane] = (i8)__float2int_rn(v * inv);
        if (lane == 0) xs[n] = am * (1.f / 127.f);
    }
}

// ---------------- once: per-(dst,rel) counts, range-binned (4 ranges) ----------------
__global__ void edge_count(const int* __restrict__ ei, const int* __restrict__ et,
                           float* __restrict__ cnt) {
    int range = blockIdx.x >> 8;
    int lo = range * (NN / 4), hi = lo + NN / 4;
    int i = (blockIdx.x & 255) * 256 + threadIdx.x;
    for (int e = i; e < NE; e += 256 * 256) {
        int d = ei[NE + e];
        if (d >= lo && d < hi)
            atomicAdd(&cnt[(size_t)d * RR + et[e]], 1.0f);
    }
}

// ---------------- once: exclusive scan of degree (= row-sum of cnt) -> offs ----------------
__global__ void scan1(const float* __restrict__ cnt, int* __restrict__ offs, int* __restrict__ bsum) {
    __shared__ int sh[256];
    int b = blockIdx.x, t = threadIdx.x;
    int i = b * 256 + t;
    int v = 0;
    if (i < NN) {
        float s = 0.f;
#pragma unroll
        for (int r = 0; r < RR; ++r) s += cnt[(size_t)i * RR + r];
        v = (int)s;
    }
    sh[t] = v;
    __syncthreads();
    for (int s = 1; s < 256; s <<= 1) {
        int tmp = (t >= s) ? sh[t - s] : 0;
        __syncthreads();
        sh[t] += tmp;
        __syncthreads();
    }
    if (i < NN) offs[i] = sh[t] - v;
    if (t == 255) bsum[b] = sh[255];
}

__global__ void scan2(int* __restrict__ bsum, int* __restrict__ offs) {
    if (threadIdx.x == 0 && blockIdx.x == 0) {
        int run = 0;
        for (int b = 0; b < SCAN_B; ++b) { int t = bsum[b]; bsum[b] = run; run += t; }
        offs[NN] = run;
    }
}

__global__ void scan3(int* __restrict__ offs, const int* __restrict__ bsum) {
    int b = blockIdx.x, t = threadIdx.x;
    int i = b * 256 + t;
    if (i < NN) offs[i] += bsum[b];
}

// ---------------- once: per-(node,rel) segment bases from offs + cnt ----------------
__global__ void offs2k(const int* __restrict__ offs, const float* __restrict__ cnt,
                       int* __restrict__ offs2) {
    int n = blockIdx.x * blockDim.x + threadIdx.x;
    if (n < NN) {
        int base = offs[n];
#pragma unroll
        for (int r = 0; r < RR; ++r) {
            offs2[n * RR + r] = base;
            base += (int)cnt[(size_t)n * RR + r];
        }
    }
}

// ---------------- once: place edges (dst,rel)-sorted, range-binned; esrt = plain src ----------------
__global__ void place(const int* __restrict__ ei, const int* __restrict__ et,
                      const int* __restrict__ offs2, int* __restrict__ fill2,
                      unsigned* __restrict__ esrt) {
    int range = blockIdx.x >> 8;
    int lo = range * (NN / 4), hi = lo + NN / 4;
    int i = (blockIdx.x & 255) * 256 + threadIdx.x;
    for (int e = i; e < NE; e += 256 * 256) {
        int d = ei[NE + e];
        if (d >= lo && d < hi) {
            int key = d * RR + et[e];
            int pos = offs2[key] + atomicAdd(&fill2[key], 1);
            esrt[pos] = (unsigned)ei[e];
        }
    }
}

// ---------------- fused per layer: segment aggregate(int8) -> LDS A-frags -> MFMA GEMM ----------------
#define RDL(X, L) __builtin_amdgcn_readlane((int)(X), (L))

// Per (node, relation) segment: FIXED register accumulator — no per-edge dispatch.
#define SEG(rr, ar) {                                                           \
    int len = (int)crow[rr];                                                    \
    int je = jb + len;                                                          \
    float a = 0.f;                                                              \
    int j = jb;                                                                 \
    for (; j + 4 <= je; j += 4) {                                               \
        unsigned m4 = esrt[j + (lane & 3)];                                     \
        float scl = xs[m4];                                                     \
        int scb = __float_as_int(scl);                                          \
        int s0 = RDL(m4, 0), s1 = RDL(m4, 1), s2 = RDL(m4, 2), s3 = RDL(m4, 3); \
        float q0 = (float)x8[(size_t)(unsigned)s0 * 64 + lane];                 \
        float q1 = (float)x8[(size_t)(unsigned)s1 * 64 + lane];                 \
        float q2 = (float)x8[(size_t)(unsigned)s2 * 64 + lane];                 \
        float q3 = (float)x8[(size_t)(unsigned)s3 * 64 + lane];                 \
        a += q0 * __int_as_float(RDL(scb, 0));                                  \
        a += q1 * __int_as_float(RDL(scb, 1));                                  \
        a += q2 * __int_as_float(RDL(scb, 2));                                  \
        a += q3 * __int_as_float(RDL(scb, 3));                                  \
    }                                                                           \
    for (; j < je; ++j) {                                                       \
        int s0 = __builtin_amdgcn_readfirstlane((int)esrt[j]);                  \
        a += (float)x8[(size_t)(unsigned)s0 * 64 + lane] * xs[(unsigned)s0];    \
    }                                                                           \
    jb = je;                                                                    \
    ar = a / fmaxf((float)len, 1.f); }

// 1024 threads = 16 waves; one node per wave; GEMM by waves 0..CT-1 (rest retire early).
template <int O, bool RELU, bool STATS>
__global__ __launch_bounds__(1024, 8) void agg_gemm(const int* __restrict__ offs,
                                                    const unsigned* __restrict__ esrt,
                                                    const float* __restrict__ cnt,
                                                    const i8* __restrict__ x8,
                                                    const float* __restrict__ xs,
                                                    const bfu* __restrict__ xb,
                                                    const bfu* __restrict__ Wp,
                                                    const float* __restrict__ bias,
                                                    float* __restrict__ outp,
                                                    float* __restrict__ stats) {
    constexpr int CT = O / 16;
    __shared__ bfu Af[1152 * 8];                     // 18 k-tiles x 64 lanes x 8 bf16 = 18KB
    int wave = threadIdx.x >> 6, lane = threadIdx.x & 63;
    int n0 = blockIdx.x * 16;
    int row = wave;                                   // one node per wave
    int n = n0 + row;
    int c = lane;
    int swz_lo = ((c >> 3) & 3) << 4;

    const float* crow = &cnt[(size_t)n * RR];
    int jb = offs[n];
    float a0, a1, a2, a3, a4, a5, a6, a7;
    SEG(0, a0) SEG(1, a1) SEG(2, a2) SEG(3, a3)
    SEG(4, a4) SEG(5, a5) SEG(6, a6) SEG(7, a7)

    // write A-fragments (granule-XOR-swizzled; verified rounds 7-12); values pre-normalized
#define WR(r, ar) {                                                            \
    bfu bv = f2bf(ar);                                                         \
    int g = (2 * (r) + (c >> 5)) * 64 + (row | swz_lo);                        \
    int gs = g ^ ((g >> 3) & 7) ^ ((g >> 6) & 7);                              \
    Af[gs * 8 + (c & 7)] = bv; }
    WR(0, a0) WR(1, a1) WR(2, a2) WR(3, a3)
    WR(4, a4) WR(5, a5) WR(6, a6) WR(7, a7)
#undef WR
    {   // root-input columns k=512+c (kt = 16,17), full bf16 precision
        bfu bv = xb[(size_t)n * 64 + lane];
        int g = (16 + (c >> 5)) * 64 + (row | swz_lo);
        int gs = g ^ ((g >> 3) & 7) ^ ((g >> 6) & 7);
        Af[gs * 8 + (c & 7)] = bv;
    }
    __syncthreads();

    int ct = wave;
    if (ct < CT) {                                    // remaining waves retire early
        f32x4 acc = (f32x4){0.f, 0.f, 0.f, 0.f};
#pragma unroll
        for (int kt = 0; kt < 18; ++kt) {
            int g = kt * 64 + lane;
            int gs = g ^ ((g >> 3) & 7) ^ ((g >> 6) & 7);
            bf16x8 af = *(const bf16x8*)&Af[gs * 8];
            bf16x8 bfv = *(const bf16x8*)&Wp[((size_t)(kt * CT + ct) * 64 + lane) * 8];
            acc = __builtin_amdgcn_mfma_f32_16x16x32_bf16(af, bfv, acc, 0, 0, 0);
        }
        int col = ct * 16 + (lane & 15);
        float b = bias[col];
        float ssum = 0.f, sq = 0.f;
#pragma unroll
        for (int jj = 0; jj < 4; ++jj) {
            int orow = (lane >> 4) * 4 + jj;
            float v = acc[jj] + b;
            if (RELU) v = fmaxf(v, 0.f);
            outp[(size_t)(n0 + orow) * O + col] = v;
            if (STATS) { ssum += v; sq += v * v; }
        }
        if (STATS) {
            ssum += __shfl_xor(ssum, 16); ssum += __shfl_xor(ssum, 32);
            sq   += __shfl_xor(sq, 16);   sq   += __shfl_xor(sq, 32);
            if ((lane >> 4) == 0) {
                int g = blockIdx.x & (NGRP - 1);
                atomicAdd(&stats[g * 128 + col], ssum);
                atomicAdd(&stats[g * 128 + 64 + col], sq);
            }
        }
    }
}

// ---------------- BN: finalize + apply; emits bf16 + row-scaled int8 ----------------
template <bool HASRES>
__global__ __launch_bounds__(256) void bn_apply(const float* __restrict__ y,
                                                const float* __restrict__ stats,
                                                const float* __restrict__ gamma,
                                                const float* __restrict__ beta,
                                                const bfu* __restrict__ resb,
                                                bfu* __restrict__ hb,
                                                i8* __restrict__ h8,
                                                float* __restrict__ hs) {
    __shared__ float sc[128];
    int t = threadIdx.x;
    if (t < 64) {
        float s = 0.f, q = 0.f;
        for (int g = 0; g < NGRP; ++g) {
            s += stats[g * 128 + t];
            q += stats[g * 128 + 64 + t];
        }
        float mu = s / (float)NN;
        float var = q / (float)NN - mu * mu;
        float scale = gamma[t] * rsqrtf(var + EPSV);
        sc[t] = scale;
        sc[64 + t] = beta[t] - mu * scale;
    }
    __syncthreads();
    int wv = threadIdx.x >> 6, lane = threadIdx.x & 63;
    int gw = blockIdx.x * 4 + wv, nw = gridDim.x * 4;
    for (int n = gw; n < NN; n += nw) {
        float v = y[(size_t)n * 64 + lane] * sc[lane] + sc[64 + lane];
        if (HASRES) v += bf2f(resb[(size_t)n * 64 + lane]);
        hb[(size_t)n * 64 + lane] = f2bf(v);
        float am = fabsf(v);
#pragma unroll
        for (int d = 1; d < 64; d <<= 1) am = fmaxf(am, __shfl_xor(am, d));
        am = fmaxf(am, 1e-20f);
        float inv = 127.f / am;
        h8[(size_t)n * 64 + lane] = (i8)__float2int_rn(v * inv);
        if (lane == 0) hs[n] = am * (1.f / 127.f);
    }
}

extern "C" void kernel_launch(void* const* d_in, const int* in_sizes, int n_in,
                              void* d_out, int out_size, void* d_ws, size_t ws_size,
                              hipStream_t stream) {
    const float* x      = (const float*)d_in[0];
    const int*   ei     = (const int*)d_in[1];
    const int*   et     = (const int*)d_in[2];
    const float* comp1  = (const float*)d_in[3];
    const float* bases1 = (const float*)d_in[4];
    const float* root1  = (const float*)d_in[5];
    const float* bias1  = (const float*)d_in[6];
    const float* comp2  = (const float*)d_in[7];
    const float* bases2 = (const float*)d_in[8];
    const float* root2  = (const float*)d_in[9];
    const float* bias2  = (const float*)d_in[10];
    const float* comp3  = (const float*)d_in[11];
    const float* bases3 = (const float*)d_in[12];
    const float* root3  = (const float*)d_in[13];
    const float* bias3  = (const float*)d_in[14];
    const float* gamma1 = (const float*)d_in[15];
    const float* beta1  = (const float*)d_in[16];
    const float* gamma2 = (const float*)d_in[17];
    const float* beta2  = (const float*)d_in[18];
    float* out = (float*)d_out;

    float* ws = (float*)d_ws;
    size_t off = 0;
    bfu* Wp1 = (bfu*)(ws + off); off += 18432;                // 36864 bf16
    bfu* Wp2 = (bfu*)(ws + off); off += 18432;
    bfu* Wp3 = (bfu*)(ws + off); off += 9216;                 // 18432 bf16
    float* cnt    = ws + off; off += (size_t)NN * RR;         // -- zero region start
    int*   fill2  = (int*)(ws + off); off += (size_t)NN * RR;
    float* stats1 = ws + off; off += NGRP * 128;
    float* stats2 = ws + off; off += NGRP * 128;              // -- zero region end
    float* y  = ws + off; off += (size_t)NN * 64;
    bfu* xb   = (bfu*)(ws + off); off += (size_t)NN * 32;
    bfu* h1b  = (bfu*)(ws + off); off += (size_t)NN * 32;
    bfu* hb   = (bfu*)(ws + off); off += (size_t)NN * 32;
    i8*  x8   = (i8*)(ws + off);  off += (size_t)NN * 16;
    i8*  h1_8 = (i8*)(ws + off);  off += (size_t)NN * 16;
    i8*  h_8  = (i8*)(ws + off);  off += (size_t)NN * 16;
    float* xsc  = ws + off; off += NN;
    float* h1sc = ws + off; off += NN;
    float* hsc  = ws + off; off += NN;
    int* offs  = (int*)(ws + off); off += NN + 4;
    int* bsum  = (int*)(ws + off); off += 256;
    int* offs2 = (int*)(ws + off); off += (size_t)NN * RR;
    unsigned* esrt = (unsigned*)(ws + off); off += NE;

    // ---- once: prep (W pack + zeros), cvt, counts, CSR sorted by (dst,rel) ----
    prep<<<dim3(1024), dim3(256), 0, stream>>>(comp1, bases1, root1, Wp1,
                                               comp2, bases2, root2, Wp2,
                                               comp3, bases3, root3, Wp3, cnt);
    cvt_rows<<<dim3(512), dim3(256), 0, stream>>>(x, xb, x8, xsc);
    edge_count<<<dim3(1024), dim3(256), 0, stream>>>(ei, et, cnt);
    scan1<<<dim3(SCAN_B), dim3(256), 0, stream>>>(cnt, offs, bsum);
    scan2<<<dim3(1), dim3(64), 0, stream>>>(bsum, offs);
    scan3<<<dim3(SCAN_B), dim3(256), 0, stream>>>(offs, bsum);
    offs2k<<<dim3(SCAN_B), dim3(256), 0, stream>>>(offs, cnt, offs2);
    place<<<dim3(1024), dim3(256), 0, stream>>>(ei, et, offs2, fill2, esrt);

    // ---- layer 1 ----
    agg_gemm<64, true, true><<<dim3(NN / 16), dim3(1024), 0, stream>>>(offs, esrt, cnt, x8, xsc, xb, Wp1, bias1, y, stats1);
    bn_apply<false><<<dim3(1024), dim3(256), 0, stream>>>(y, stats1, gamma1, beta1, nullptr, h1b, h1_8, h1sc);

    // ---- layer 2 ----
    agg_gemm<64, true, true><<<dim3(NN / 16), dim3(1024), 0, stream>>>(offs, esrt, cnt, h1_8, h1sc, h1b, Wp2, bias2, y, stats2);
    bn_apply<true><<<dim3(1024), dim3(256), 0, stream>>>(y, stats2, gamma2, beta2, h1b, hb, h_8, hsc);

    // ---- layer 3 (output) ----
    agg_gemm<32, false, false><<<dim3(NN / 16), dim3(1024), 0, stream>>>(offs, esrt, cnt, h_8, hsc, hb, Wp3, bias3, out, nullptr);
}

// Round 14
// 391.682 us; speedup vs baseline: 1.3448x; 1.0102x over previous
//
#include <hip/hip_runtime.h>

#define NN 50000
#define NE 800000
#define RR 8
#define BB 8
#define EPSV 1e-5f
#define SCAN_B ((NN + 255) / 256)   // 196
#define NGRP 64

typedef unsigned short bfu;
typedef signed char i8;
typedef __attribute__((ext_vector_type(8))) short bf16x8;
typedef __attribute__((ext_vector_type(4))) float f32x4;

__device__ inline float bf2f(bfu u) { return __uint_as_float(((unsigned)u) << 16); }
__device__ inline bfu f2bf(float f) {
    unsigned u = __float_as_uint(f);
    return (bfu)((u + 0x7fffu + ((u >> 16) & 1u)) >> 16);   // RTNE
}

#define NW1 36864L
#define NW2 36864L
#define NW3 18432L
// zero region: cnt (NN*8 f32) + fill2 (NN*8 i32) + stats1 + stats2
#define NZ  (400000L + 400000L + 2L * NGRP * 128)

// ---------------- W packing: logical W[k][o] -> MFMA B-frag layout ----------------
__device__ inline void build_one(const float* __restrict__ comp, const float* __restrict__ bases,
                                 const float* __restrict__ root, bfu* __restrict__ Wp,
                                 int O, int idx) {
    int k = idx / O, o = idx % O;
    float val;
    if (k < 512) {
        int r = k >> 6, i = k & 63;
        val = 0.f;
#pragma unroll
        for (int b = 0; b < BB; ++b)
            val += comp[r * BB + b] * bases[(b * 64 + i) * O + o];
    } else {
        val = root[(k - 512) * O + o];
    }
    int kt = k >> 5, kk = k & 31;
    int lane = ((kk >> 3) << 4) | (o & 15);
    int pos = ((kt * (O / 16) + (o >> 4)) * 64 + lane) * 8 + (kk & 7);
    Wp[pos] = f2bf(val);
}

// ---------------- once: W builds + zero (cnt|fill2|stats1|stats2) ----------------
__global__ void prep(const float* __restrict__ c1, const float* __restrict__ b1,
                     const float* __restrict__ r1, bfu* __restrict__ Wp1,
                     const float* __restrict__ c2, const float* __restrict__ b2,
                     const float* __restrict__ r2, bfu* __restrict__ Wp2,
                     const float* __restrict__ c3, const float* __restrict__ b3,
                     const float* __restrict__ r3, bfu* __restrict__ Wp3,
                     float* __restrict__ zbase) {
    long i = (long)blockIdx.x * blockDim.x + threadIdx.x;
    long stride = (long)gridDim.x * blockDim.x;
    const long tot = NW1 + NW2 + NW3 + NZ;
    for (; i < tot; i += stride) {
        if (i < NW1) build_one(c1, b1, r1, Wp1, 64, (int)i);
        else if (i < NW1 + NW2) build_one(c2, b2, r2, Wp2, 64, (int)(i - NW1));
        else if (i < NW1 + NW2 + NW3) build_one(c3, b3, r3, Wp3, 32, (int)(i - NW1 - NW2));
        else zbase[i - (NW1 + NW2 + NW3)] = 0.f;
    }
}

// ---------------- once: x -> xb (bf16) + x8 (int8 row-scaled) + xs (row scale) ----------------
__global__ __launch_bounds__(256) void cvt_rows(const float* __restrict__ x,
                                                bfu* __restrict__ xb,
                                                i8* __restrict__ x8,
                                                float* __restrict__ xs) {
    int wv = threadIdx.x >> 6, lane = threadIdx.x & 63;
    int gw = blockIdx.x * 4 + wv, nw = gridDim.x * 4;
    for (int n = gw; n < NN; n += nw) {
        float v = x[(size_t)n * 64 + lane];
        xb[(size_t)n * 64 + lane] = f2bf(v);
        float am = fabsf(v);
#pragma unroll
        for (int d = 1; d < 64; d <<= 1) am = fmaxf(am, __shfl_xor(am, d));
        am = fmaxf(am, 1e-20f);
        float inv = 127.f / am;
        x8[(size_t)n * 64 + lane] = (i8)__float2int_rn(v * inv);
        if (lane == 0) xs[n] = am * (1.f / 127.f);
    }
}

// ---------------- once: per-(dst,rel) counts, range-binned (4 ranges) ----------------
__global__ void edge_count(const int* __restrict__ ei, const int* __restrict__ et,
                           float* __restrict__ cnt) {
    int range = blockIdx.x >> 8;
    int lo = range * (NN / 4), hi = lo + NN / 4;
    int i = (blockIdx.x & 255) * 256 + threadIdx.x;
    for (int e = i; e < NE; e += 256 * 256) {
        int d = ei[NE + e];
        if (d >= lo && d < hi)
            atomicAdd(&cnt[(size_t)d * RR + et[e]], 1.0f);
    }
}

// ---------------- once: exclusive scan of degree (= row-sum of cnt) -> offs ----------------
__global__ void scan1(const float* __restrict__ cnt, int* __restrict__ offs, int* __restrict__ bsum) {
    __shared__ int sh[256];
    int b = blockIdx.x, t = threadIdx.x;
    int i = b * 256 + t;
    int v = 0;
    if (i < NN) {
        float s = 0.f;
#pragma unroll
        for (int r = 0; r < RR; ++r) s += cnt[(size_t)i * RR + r];
        v = (int)s;
    }
    sh[t] = v;
    __syncthreads();
    for (int s = 1; s < 256; s <<= 1) {
        int tmp = (t >= s) ? sh[t - s] : 0;
        __syncthreads();
        sh[t] += tmp;
        __syncthreads();
    }
    if (i < NN) offs[i] = sh[t] - v;
    if (t == 255) bsum[b] = sh[255];
}

__global__ void scan2(int* __restrict__ bsum, int* __restrict__ offs) {
    if (threadIdx.x == 0 && blockIdx.x == 0) {
        int run = 0;
        for (int b = 0; b < SCAN_B; ++b) { int t = bsum[b]; bsum[b] = run; run += t; }
        offs[NN] = run;
    }
}

__global__ void scan3(int* __restrict__ offs, const int* __restrict__ bsum) {
    int b = blockIdx.x, t = threadIdx.x;
    int i = b * 256 + t;
    if (i < NN) offs[i] += bsum[b];
}

// ---------------- once: per-(node,rel) segment bases from offs + cnt ----------------
__global__ void offs2k(const int* __restrict__ offs, const float* __restrict__ cnt,
                       int* __restrict__ offs2) {
    int n = blockIdx.x * blockDim.x + threadIdx.x;
    if (n < NN) {
        int base = offs[n];
#pragma unroll
        for (int r = 0; r < RR; ++r) {
            offs2[n * RR + r] = base;
            base += (int)cnt[(size_t)n * RR + r];
        }
    }
}

// ---------------- once: place edges (dst,rel)-sorted, range-binned; esrt = plain src ----------------
__global__ void place(const int* __restrict__ ei, const int* __restrict__ et,
                      const int* __restrict__ offs2, int* __restrict__ fill2,
                      unsigned* __restrict__ esrt) {
    int range = blockIdx.x >> 8;
    int lo = range * (NN / 4), hi = lo + NN / 4;
    int i = (blockIdx.x & 255) * 256 + threadIdx.x;
    for (int e = i; e < NE; e += 256 * 256) {
        int d = ei[NE + e];
        if (d >= lo && d < hi) {
            int key = d * RR + et[e];
            int pos = offs2[key] + atomicAdd(&fill2[key], 1);
            esrt[pos] = (unsigned)ei[e];
        }
    }
}

// ---------------- per layer: edge-parallel gather into G (esrt order) + gsc ----------------
// wave-iter = 16 edges; 16-lane group g copies row of edge 4k+g via uchar4/lane.
__global__ __launch_bounds__(256) void gather_G(const unsigned* __restrict__ esrt,
                                                const i8* __restrict__ x8,
                                                const float* __restrict__ xs,
                                                i8* __restrict__ G,
                                                float* __restrict__ gsc) {
    int wave = (int)((blockIdx.x * 256 + threadIdx.x) >> 6);
    int lane = threadIdx.x & 63;
    int nwaves = (gridDim.x * 256) >> 6;
    int q = lane >> 4, b4 = (lane & 15) * 4;
    for (int it = wave; it < NE / 16; it += nwaves) {
        int j16 = it * 16;
        unsigned mye = esrt[j16 + (lane & 15)];      // 16 srcs in lanes 0-15 (replicated)
        if (lane < 16) gsc[j16 + lane] = xs[mye];    // per-edge scale
#pragma unroll
        for (int k = 0; k < 4; ++k) {
            int e = 4 * k + q;                        // group q handles edge 4k+q
            int src = __shfl((int)mye, e);
            unsigned v = *(const unsigned*)&x8[(size_t)(unsigned)src * 64 + b4];
            *(unsigned*)&G[(size_t)(j16 + e) * 64 + b4] = v;   // 4 rows = 256B contiguous
        }
    }
}

// ---------------- fused per layer: streamed segment-sum over G -> LDS A-frags -> MFMA GEMM ----------------
#define RDL(X, L) __builtin_amdgcn_readlane((int)(X), (L))

// Per (node, relation) segment: consecutive G rows, independent streamed loads.
#define SEG(rr, ar) {                                                           \
    int len = (int)crow[rr];                                                    \
    int je = jb + len;                                                          \
    float a = 0.f;                                                              \
    int j = jb;                                                                 \
    for (; j + 4 <= je; j += 4) {                                               \
        float gq = gsc[j + (lane & 3)];                                         \
        int gqb = __float_as_int(gq);                                           \
        float q0 = (float)G[(size_t)j * 64 + lane];                             \
        float q1 = (float)G[(size_t)(j + 1) * 64 + lane];                       \
        float q2 = (float)G[(size_t)(j + 2) * 64 + lane];                       \
        float q3 = (float)G[(size_t)(j + 3) * 64 + lane];                       \
        a += q0 * __int_as_float(RDL(gqb, 0));                                  \
        a += q1 * __int_as_float(RDL(gqb, 1));                                  \
        a += q2 * __int_as_float(RDL(gqb, 2));                                  \
        a += q3 * __int_as_float(RDL(gqb, 3));                                  \
    }                                                                           \
    for (; j < je; ++j)                                                         \
        a += (float)G[(size_t)j * 64 + lane] * gsc[j];                          \
    jb = je;                                                                    \
    ar = a / fmaxf((float)len, 1.f); }

// 1024 threads = 16 waves; one node per wave; GEMM by waves 0..CT-1 (rest retire early).
template <int O, bool RELU, bool STATS>
__global__ __launch_bounds__(1024, 8) void agg_gemm(const int* __restrict__ offs,
                                                    const i8* __restrict__ G,
                                                    const float* __restrict__ gsc,
                                                    const float* __restrict__ cnt,
                                                    const bfu* __restrict__ xb,
                                                    const bfu* __restrict__ Wp,
                                                    const float* __restrict__ bias,
                                                    float* __restrict__ outp,
                                                    float* __restrict__ stats) {
    constexpr int CT = O / 16;
    __shared__ bfu Af[1152 * 8];                     // 18 k-tiles x 64 lanes x 8 bf16 = 18KB
    int wave = threadIdx.x >> 6, lane = threadIdx.x & 63;
    int n0 = blockIdx.x * 16;
    int row = wave;                                   // one node per wave
    int n = n0 + row;
    int c = lane;
    int swz_lo = ((c >> 3) & 3) << 4;

    const float* crow = &cnt[(size_t)n * RR];
    int jb = offs[n];
    float a0, a1, a2, a3, a4, a5, a6, a7;
    SEG(0, a0) SEG(1, a1) SEG(2, a2) SEG(3, a3)
    SEG(4, a4) SEG(5, a5) SEG(6, a6) SEG(7, a7)

    // write A-fragments (granule-XOR-swizzled; verified rounds 7-13); values pre-normalized
#define WR(r, ar) {                                                            \
    bfu bv = f2bf(ar);                                                         \
    int g = (2 * (r) + (c >> 5)) * 64 + (row | swz_lo);                        \
    int gs = g ^ ((g >> 3) & 7) ^ ((g >> 6) & 7);                              \
    Af[gs * 8 + (c & 7)] = bv; }
    WR(0, a0) WR(1, a1) WR(2, a2) WR(3, a3)
    WR(4, a4) WR(5, a5) WR(6, a6) WR(7, a7)
#undef WR
    {   // root-input columns k=512+c (kt = 16,17), full bf16 precision
        bfu bv = xb[(size_t)n * 64 + lane];
        int g = (16 + (c >> 5)) * 64 + (row | swz_lo);
        int gs = g ^ ((g >> 3) & 7) ^ ((g >> 6) & 7);
        Af[gs * 8 + (c & 7)] = bv;
    }
    __syncthreads();

    int ct = wave;
    if (ct < CT) {                                    // remaining waves retire early
        f32x4 acc = (f32x4){0.f, 0.f, 0.f, 0.f};
#pragma unroll
        for (int kt = 0; kt < 18; ++kt) {
            int g = kt * 64 + lane;
            int gs = g ^ ((g >> 3) & 7) ^ ((g >> 6) & 7);
            bf16x8 af = *(const bf16x8*)&Af[gs * 8];
            bf16x8 bfv = *(const bf16x8*)&Wp[((size_t)(kt * CT + ct) * 64 + lane) * 8];
            acc = __builtin_amdgcn_mfma_f32_16x16x32_bf16(af, bfv, acc, 0, 0, 0);
        }
        int col = ct * 16 + (lane & 15);
        float b = bias[col];
        float ssum = 0.f, sq = 0.f;
#pragma unroll
        for (int jj = 0; jj < 4; ++jj) {
            int orow = (lane >> 4) * 4 + jj;
            float v = acc[jj] + b;
            if (RELU) v = fmaxf(v, 0.f);
            outp[(size_t)(n0 + orow) * O + col] = v;
            if (STATS) { ssum += v; sq += v * v; }
        }
        if (STATS) {
            ssum += __shfl_xor(ssum, 16); ssum += __shfl_xor(ssum, 32);
            sq   += __shfl_xor(sq, 16);   sq   += __shfl_xor(sq, 32);
            if ((lane >> 4) == 0) {
                int g = blockIdx.x & (NGRP - 1);
                atomicAdd(&stats[g * 128 + col], ssum);
                atomicAdd(&stats[g * 128 + 64 + col], sq);
            }
        }
    }
}

// ---------------- BN: finalize + apply; emits bf16 + row-scaled int8 ----------------
template <bool HASRES>
__global__ __launch_bounds__(256) void bn_apply(const float* __restrict__ y,
                                                const float* __restrict__ stats,
                                                const float* __restrict__ gamma,
                                                const float* __restrict__ beta,
                                                const bfu* __restrict__ resb,
                                                bfu* __restrict__ hb,
                                                i8* __restrict__ h8,
                                                float* __restrict__ hs) {
    __shared__ float sc[128];
    int t = threadIdx.x;
    if (t < 64) {
        float s = 0.f, q = 0.f;
        for (int g = 0; g < NGRP; ++g) {
            s += stats[g * 128 + t];
            q += stats[g * 128 + 64 + t];
        }
        float mu = s / (float)NN;
        float var = q / (float)NN - mu * mu;
        float scale = gamma[t] * rsqrtf(var + EPSV);
        sc[t] = scale;
        sc[64 + t] = beta[t] - mu * scale;
    }
    __syncthreads();
    int wv = threadIdx.x >> 6, lane = threadIdx.x & 63;
    int gw = blockIdx.x * 4 + wv, nw = gridDim.x * 4;
    for (int n = gw; n < NN; n += nw) {
        float v = y[(size_t)n * 64 + lane] * sc[lane] + sc[64 + lane];
        if (HASRES) v += bf2f(resb[(size_t)n * 64 + lane]);
        hb[(size_t)n * 64 + lane] = f2bf(v);
        float am = fabsf(v);
#pragma unroll
        for (int d = 1; d < 64; d <<= 1) am = fmaxf(am, __shfl_xor(am, d));
        am = fmaxf(am, 1e-20f);
        float inv = 127.f / am;
        h8[(size_t)n * 64 + lane] = (i8)__float2int_rn(v * inv);
        if (lane == 0) hs[n] = am * (1.f / 127.f);
    }
}

extern "C" void kernel_launch(void* const* d_in, const int* in_sizes, int n_in,
                              void* d_out, int out_size, void* d_ws, size_t ws_size,
                              hipStream_t stream) {
    const float* x      = (const float*)d_in[0];
    const int*   ei     = (const int*)d_in[1];
    const int*   et     = (const int*)d_in[2];
    const float* comp1  = (const float*)d_in[3];
    const float* bases1 = (const float*)d_in[4];
    const float* root1  = (const float*)d_in[5];
    const float* bias1  = (const float*)d_in[6];
    const float* comp2  = (const float*)d_in[7];
    const float* bases2 = (const float*)d_in[8];
    const float* root2  = (const float*)d_in[9];
    const float* bias2  = (const float*)d_in[10];
    const float* comp3  = (const float*)d_in[11];
    const float* bases3 = (const float*)d_in[12];
    const float* root3  = (const float*)d_in[13];
    const float* bias3  = (const float*)d_in[14];
    const float* gamma1 = (const float*)d_in[15];
    const float* beta1  = (const float*)d_in[16];
    const float* gamma2 = (const float*)d_in[17];
    const float* beta2  = (const float*)d_in[18];
    float* out = (float*)d_out;

    float* ws = (float*)d_ws;
    size_t off = 0;
    bfu* Wp1 = (bfu*)(ws + off); off += 18432;                // 36864 bf16
    bfu* Wp2 = (bfu*)(ws + off); off += 18432;
    bfu* Wp3 = (bfu*)(ws + off); off += 9216;                 // 18432 bf16
    float* cnt    = ws + off; off += (size_t)NN * RR;         // -- zero region start
    int*   fill2  = (int*)(ws + off); off += (size_t)NN * RR;
    float* stats1 = ws + off; off += NGRP * 128;
    float* stats2 = ws + off; off += NGRP * 128;              // -- zero region end
    float* y  = ws + off; off += (size_t)NN * 64;
    bfu* xb   = (bfu*)(ws + off); off += (size_t)NN * 32;
    bfu* h1b  = (bfu*)(ws + off); off += (size_t)NN * 32;
    bfu* hb   = (bfu*)(ws + off); off += (size_t)NN * 32;
    i8*  x8   = (i8*)(ws + off);  off += (size_t)NN * 16;
    i8*  h1_8 = (i8*)(ws + off);  off += (size_t)NN * 16;
    i8*  h_8  = (i8*)(ws + off);  off += (size_t)NN * 16;
    float* xsc  = ws + off; off += NN;
    float* h1sc = ws + off; off += NN;
    float* hsc  = ws + off; off += NN;
    int* offs  = (int*)(ws + off); off += NN + 4;
    int* bsum  = (int*)(ws + off); off += 256;
    int* offs2 = (int*)(ws + off); off += (size_t)NN * RR;
    unsigned* esrt = (unsigned*)(ws + off); off += NE;
    i8* G      = (i8*)(ws + off); off += (size_t)NE * 16;     // 51.2MB gathered rows
    float* gsc = ws + off; off += NE;                         // per-edge scales

    // ---- once: prep (W pack + zeros), cvt, counts, CSR sorted by (dst,rel) ----
    prep<<<dim3(1024), dim3(256), 0, stream>>>(comp1, bases1, root1, Wp1,
                                               comp2, bases2, root2, Wp2,
                                               comp3, bases3, root3, Wp3, cnt);
    cvt_rows<<<dim3(512), dim3(256), 0, stream>>>(x, xb, x8, xsc);
    edge_count<<<dim3(1024), dim3(256), 0, stream>>>(ei, et, cnt);
    scan1<<<dim3(SCAN_B), dim3(256), 0, stream>>>(cnt, offs, bsum);
    scan2<<<dim3(1), dim3(64), 0, stream>>>(bsum, offs);
    scan3<<<dim3(SCAN_B), dim3(256), 0, stream>>>(offs, bsum);
    offs2k<<<dim3(SCAN_B), dim3(256), 0, stream>>>(offs, cnt, offs2);
    place<<<dim3(1024), dim3(256), 0, stream>>>(ei, et, offs2, fill2, esrt);

    // ---- layer 1 ----
    gather_G<<<dim3(2048), dim3(256), 0, stream>>>(esrt, x8, xsc, G, gsc);
    agg_gemm<64, true, true><<<dim3(NN / 16), dim3(1024), 0, stream>>>(offs, G, gsc, cnt, xb, Wp1, bias1, y, stats1);
    bn_apply<false><<<dim3(1024), dim3(256), 0, stream>>>(y, stats1, gamma1, beta1, nullptr, h1b, h1_8, h1sc);

    // ---- layer 2 ----
    gather_G<<<dim3(2048), dim3(256), 0, stream>>>(esrt, h1_8, h1sc, G, gsc);
    agg_gemm<64, true, true><<<dim3(NN / 16), dim3(1024), 0, stream>>>(offs, G, gsc, cnt, h1b, Wp2, bias2, y, stats2);
    bn_apply<true><<<dim3(1024), dim3(256), 0, stream>>>(y, stats2, gamma2, beta2, h1b, hb, h_8, hsc);

    // ---- layer 3 (output) ----
    gather_G<<<dim3(2048), dim3(256), 0, stream>>>(esrt, h_8, hsc, G, gsc);
    agg_gemm<32, false, false><<<dim3(NN / 16), dim3(1024), 0, stream>>>(offs, G, gsc, cnt, hb, Wp3, bias3, out, nullptr);
}

// Round 15
// 318.456 us; speedup vs baseline: 1.6540x; 1.2299x over previous
//
#include <hip/hip_runtime.h>

#define NN 50000
#define NE 800000
#define RR 8
#define BB 8
#define EPSV 1e-5f
#define SCAN_B ((NN + 255) / 256)   // 196
#define NGRP 64

typedef unsigned short bfu;
typedef __attribute__((ext_vector_type(8))) short bf16x8;
typedef __attribute__((ext_vector_type(4))) float f32x4;

__device__ inline float bf2f(bfu u) { return __uint_as_float(((unsigned)u) << 16); }
__device__ inline bfu f2bf(float f) {
    unsigned u = __float_as_uint(f);
    return (bfu)((u + 0x7fffu + ((u >> 16) & 1u)) >> 16);   // RTNE
}

#define NW1 36864L
#define NW2 36864L
#define NW3 18432L
#define NCV ((long)NN * 64)
#define NZ  (400000L + 50000L + 2L * NGRP * 128)

// ---------------- W packing: logical W[k][o] -> MFMA B-frag layout ----------------
__device__ inline void build_one(const float* __restrict__ comp, const float* __restrict__ bases,
                                 const float* __restrict__ root, bfu* __restrict__ Wp,
                                 int O, int idx) {
    int k = idx / O, o = idx % O;
    float val;
    if (k < 512) {
        int r = k >> 6, i = k & 63;
        val = 0.f;
#pragma unroll
        for (int b = 0; b < BB; ++b)
            val += comp[r * BB + b] * bases[(b * 64 + i) * O + o];
    } else {
        val = root[(k - 512) * O + o];
    }
    int kt = k >> 5, kk = k & 31;
    int lane = ((kk >> 3) << 4) | (o & 15);
    int pos = ((kt * (O / 16) + (o >> 4)) * 64 + lane) * 8 + (kk & 7);
    Wp[pos] = f2bf(val);
}

// ---------------- once: W builds + x->bf16 + zero (cnt|fill|stats1|stats2) ----------------
__global__ void prep(const float* __restrict__ c1, const float* __restrict__ b1,
                     const float* __restrict__ r1, bfu* __restrict__ Wp1,
                     const float* __restrict__ c2, const float* __restrict__ b2,
                     const float* __restrict__ r2, bfu* __restrict__ Wp2,
                     const float* __restrict__ c3, const float* __restrict__ b3,
                     const float* __restrict__ r3, bfu* __restrict__ Wp3,
                     const float* __restrict__ x, bfu* __restrict__ xb,
                     float* __restrict__ zbase) {
    long i = (long)blockIdx.x * blockDim.x + threadIdx.x;
    long stride = (long)gridDim.x * blockDim.x;
    const long tot = NW1 + NW2 + NW3 + NCV + NZ;
    for (; i < tot; i += stride) {
        if (i < NW1) build_one(c1, b1, r1, Wp1, 64, (int)i);
        else if (i < NW1 + NW2) build_one(c2, b2, r2, Wp2, 64, (int)(i - NW1));
        else if (i < NW1 + NW2 + NW3) build_one(c3, b3, r3, Wp3, 32, (int)(i - NW1 - NW2));
        else if (i < NW1 + NW2 + NW3 + NCV) { long k = i - NW1 - NW2 - NW3; xb[k] = f2bf(x[k]); }
        else zbase[i - (NW1 + NW2 + NW3 + NCV)] = 0.f;
    }
}

// ---------------- once: per-(dst,rel) counts, range-binned (8 ranges) ----------------
__global__ void edge_count(const int* __restrict__ ei, const int* __restrict__ et,
                           float* __restrict__ cnt) {
    int range = blockIdx.x >> 8;
    int lo = range * (NN / 8), hi = lo + NN / 8;
    int i = (blockIdx.x & 255) * 256 + threadIdx.x;
    for (int e = i; e < NE; e += 256 * 256) {
        int d = ei[NE + e];
        if (d >= lo && d < hi)
            atomicAdd(&cnt[(size_t)d * RR + et[e]], 1.0f);
    }
}

// ---------------- once: exclusive scan of degree -> offs ----------------
__global__ void scan1(const float* __restrict__ cnt, int* __restrict__ offs, int* __restrict__ bsum) {
    __shared__ int sh[256];
    int b = blockIdx.x, t = threadIdx.x;
    int i = b * 256 + t;
    int v = 0;
    if (i < NN) {
        float s = 0.f;
#pragma unroll
        for (int r = 0; r < RR; ++r) s += cnt[(size_t)i * RR + r];
        v = (int)s;
    }
    sh[t] = v;
    __syncthreads();
    for (int s = 1; s < 256; s <<= 1) {
        int tmp = (t >= s) ? sh[t - s] : 0;
        __syncthreads();
        sh[t] += tmp;
        __syncthreads();
    }
    if (i < NN) offs[i] = sh[t] - v;
    if (t == 255) bsum[b] = sh[255];
}

__global__ void scan2(int* __restrict__ bsum, int* __restrict__ offs) {
    if (threadIdx.x == 0 && blockIdx.x == 0) {
        int run = 0;
        for (int b = 0; b < SCAN_B; ++b) { int t = bsum[b]; bsum[b] = run; run += t; }
        offs[NN] = run;
    }
}

__global__ void scan3(int* __restrict__ offs, const int* __restrict__ bsum) {
    int b = blockIdx.x, t = threadIdx.x;
    int i = b * 256 + t;
    if (i < NN) offs[i] += bsum[b];
}

// ---------------- once: place edges dst-sorted, range-binned (8); packed src<<3|r ----------------
__global__ void place(const int* __restrict__ ei, const int* __restrict__ et,
                      const int* __restrict__ offs, int* __restrict__ fill,
                      unsigned* __restrict__ esrt) {
    int range = blockIdx.x >> 8;
    int lo = range * (NN / 8), hi = lo + NN / 8;
    int i = (blockIdx.x & 255) * 256 + threadIdx.x;
    for (int e = i; e < NE; e += 256 * 256) {
        int d = ei[NE + e];
        if (d >= lo && d < hi) {
            int pos = offs[d] + atomicAdd(&fill[d], 1);
            esrt[pos] = ((unsigned)ei[e] << 3) | (unsigned)et[e];
        }
    }
}

// ---------------- fused per layer: aggregate -> LDS A-frags -> MFMA GEMM (+BN stats) ----------------
#define ACCUMS(SU, V, A)                       \
    switch ((SU) & 7) {                        \
        case 0: A##0 += (V); break;            \
        case 1: A##1 += (V); break;            \
        case 2: A##2 += (V); break;            \
        case 3: A##3 += (V); break;            \
        case 4: A##4 += (V); break;            \
        case 5: A##5 += (V); break;            \
        case 6: A##6 += (V); break;            \
        default: A##7 += (V); break;           \
    }
#define RFL(X) __builtin_amdgcn_readfirstlane((int)(X))
#define GATH(S) bf2f(xb[((size_t)((unsigned)(S) >> 3)) * 64 + lane])

// 8 scalar-src loads for one node
#define S8(P, J)                                                        \
    int P##0 = RFL(esrt[(J) + 0]), P##1 = RFL(esrt[(J) + 1]);           \
    int P##2 = RFL(esrt[(J) + 2]), P##3 = RFL(esrt[(J) + 3]);           \
    int P##4 = RFL(esrt[(J) + 4]), P##5 = RFL(esrt[(J) + 5]);           \
    int P##6 = RFL(esrt[(J) + 6]), P##7 = RFL(esrt[(J) + 7]);
#define G8(V, P)                                                        \
    float V##0 = GATH(P##0), V##1 = GATH(P##1), V##2 = GATH(P##2),      \
          V##3 = GATH(P##3), V##4 = GATH(P##4), V##5 = GATH(P##5),      \
          V##6 = GATH(P##6), V##7 = GATH(P##7);
#define A8(P, V, A)                                                     \
    ACCUMS(P##0, V##0, A) ACCUMS(P##1, V##1, A) ACCUMS(P##2, V##2, A)   \
    ACCUMS(P##3, V##3, A) ACCUMS(P##4, V##4, A) ACCUMS(P##5, V##5, A)   \
    ACCUMS(P##6, V##6, A) ACCUMS(P##7, V##7, A)
#define S4(P, J)                                                        \
    int P##0 = RFL(esrt[(J) + 0]), P##1 = RFL(esrt[(J) + 1]);           \
    int P##2 = RFL(esrt[(J) + 2]), P##3 = RFL(esrt[(J) + 3]);
#define G4(V, P)                                                        \
    float V##0 = GATH(P##0), V##1 = GATH(P##1), V##2 = GATH(P##2),      \
          V##3 = GATH(P##3);
#define A4(P, V, A)                                                     \
    ACCUMS(P##0, V##0, A) ACCUMS(P##1, V##1, A) ACCUMS(P##2, V##2, A)   \
    ACCUMS(P##3, V##3, A)

// normalize + write one A-fragment value (granule-XOR-swizzled; verified r7-r14)
#define WRX(r, ar, nn, rw) {                                                   \
    float inv = 1.f / fmaxf(cnt[(size_t)(nn) * RR + (r)], 1.f);                \
    bfu bv = f2bf((ar) * inv);                                                 \
    int g = (2 * (r) + (c >> 5)) * 64 + ((rw) | swz_lo);                       \
    int gs = g ^ ((g >> 3) & 7) ^ ((g >> 6) & 7);                              \
    Af[gs * 8 + (c & 7)] = bv; }

// 256 threads = 4 waves; 4 nodes/wave processed as 2 INTERLEAVED pairs (2x memory parallelism).
template <int O, bool RELU, bool STATS>
__global__ __launch_bounds__(256) void agg_gemm(const int* __restrict__ offs,
                                                const unsigned* __restrict__ esrt,
                                                const float* __restrict__ cnt,
                                                const bfu* __restrict__ xb,
                                                const bfu* __restrict__ Wp,
                                                const float* __restrict__ bias,
                                                float* __restrict__ outp,
                                                float* __restrict__ stats) {
    constexpr int CT = O / 16;
    __shared__ bfu Af[1152 * 8];                     // 18 k-tiles x 64 lanes x 8 bf16 = 18KB
    int wave = threadIdx.x >> 6, lane = threadIdx.x & 63;
    int n0 = blockIdx.x * 16;
    int c = lane;
    int swz_lo = ((c >> 3) & 3) << 4;

#pragma unroll 1
    for (int half = 0; half < 2; ++half) {
        int rowA = wave * 4 + half * 2, rowB = rowA + 1;
        int nA = n0 + rowA, nB = n0 + rowB;
        int jA = offs[nA], eA = offs[nA + 1];
        int jB = offs[nB], eB = offs[nB + 1];
        float a0 = 0.f, a1 = 0.f, a2 = 0.f, a3 = 0.f, a4 = 0.f, a5 = 0.f, a6 = 0.f, a7 = 0.f;
        float b0 = 0.f, b1 = 0.f, b2 = 0.f, b3 = 0.f, b4 = 0.f, b5 = 0.f, b6 = 0.f, b7 = 0.f;
        // interleaved main loop: both nodes' 8-batches in flight together
        while (jA + 8 <= eA && jB + 8 <= eB) {
            S8(sa, jA) S8(sb, jB)
            G8(va, sa) G8(vb, sb)
            A8(sa, va, a) A8(sb, vb, b)
            jA += 8; jB += 8;
        }
        // drain A
        while (jA + 8 <= eA) { S8(ta, jA) G8(wa, ta) A8(ta, wa, a) jA += 8; }
        if (jA + 4 <= eA) { S4(ua, jA) G4(xa, ua) A4(ua, xa, a) jA += 4; }
        for (; jA < eA; ++jA) { int s = RFL(esrt[jA]); float v = GATH(s); ACCUMS(s, v, a) }
        // drain B
        while (jB + 8 <= eB) { S8(tb, jB) G8(wb, tb) A8(tb, wb, b) jB += 8; }
        if (jB + 4 <= eB) { S4(ub, jB) G4(xc, ub) A4(ub, xc, b) jB += 4; }
        for (; jB < eB; ++jB) { int s = RFL(esrt[jB]); float v = GATH(s); ACCUMS(s, v, b) }
        // normalize + write A-fragments for both nodes
        WRX(0, a0, nA, rowA) WRX(1, a1, nA, rowA) WRX(2, a2, nA, rowA) WRX(3, a3, nA, rowA)
        WRX(4, a4, nA, rowA) WRX(5, a5, nA, rowA) WRX(6, a6, nA, rowA) WRX(7, a7, nA, rowA)
        WRX(0, b0, nB, rowB) WRX(1, b1, nB, rowB) WRX(2, b2, nB, rowB) WRX(3, b3, nB, rowB)
        WRX(4, b4, nB, rowB) WRX(5, b5, nB, rowB) WRX(6, b6, nB, rowB) WRX(7, b7, nB, rowB)
        {   // root-input columns k=512+c (kt = 16,17), full bf16 precision
            bfu bvA = xb[(size_t)nA * 64 + lane];
            int gA = (16 + (c >> 5)) * 64 + (rowA | swz_lo);
            int gsA = gA ^ ((gA >> 3) & 7) ^ ((gA >> 6) & 7);
            Af[gsA * 8 + (c & 7)] = bvA;
            bfu bvB = xb[(size_t)nB * 64 + lane];
            int gB = (16 + (c >> 5)) * 64 + (rowB | swz_lo);
            int gsB = gB ^ ((gB >> 3) & 7) ^ ((gB >> 6) & 7);
            Af[gsB * 8 + (c & 7)] = bvB;
        }
    }
    __syncthreads();

    int ct = wave;
    if (CT == 4 || ct < CT) {
        f32x4 acc = (f32x4){0.f, 0.f, 0.f, 0.f};
#pragma unroll
        for (int kt = 0; kt < 18; ++kt) {
            int g = kt * 64 + lane;
            int gs = g ^ ((g >> 3) & 7) ^ ((g >> 6) & 7);
            bf16x8 af = *(const bf16x8*)&Af[gs * 8];
            bf16x8 bfv = *(const bf16x8*)&Wp[((size_t)(kt * CT + ct) * 64 + lane) * 8];
            acc = __builtin_amdgcn_mfma_f32_16x16x32_bf16(af, bfv, acc, 0, 0, 0);
        }
        int col = ct * 16 + (lane & 15);
        float b = bias[col];
        float ssum = 0.f, sq = 0.f;
#pragma unroll
        for (int jj = 0; jj < 4; ++jj) {
            int row = (lane >> 4) * 4 + jj;
            float v = acc[jj] + b;
            if (RELU) v = fmaxf(v, 0.f);
            outp[(size_t)(n0 + row) * O + col] = v;
            if (STATS) { ssum += v; sq += v * v; }
        }
        if (STATS) {
            ssum += __shfl_xor(ssum, 16); ssum += __shfl_xor(ssum, 32);
            sq   += __shfl_xor(sq, 16);   sq   += __shfl_xor(sq, 32);
            if ((lane >> 4) == 0) {
                int g = blockIdx.x & (NGRP - 1);
                atomicAdd(&stats[g * 128 + col], ssum);
                atomicAdd(&stats[g * 128 + 64 + col], sq);
            }
        }
    }
}

// ---------------- BN: finalize (redundant per block) + apply, fused ----------------
template <bool HASRES>
__global__ __launch_bounds__(256) void bn_apply(const float* __restrict__ y,
                                                const float* __restrict__ stats,
                                                const float* __restrict__ gamma,
                                                const float* __restrict__ beta,
                                                const bfu* __restrict__ resb,
                                                bfu* __restrict__ hb) {
    __shared__ float sc[128];
    int t = threadIdx.x;
    if (t < 64) {
        float s = 0.f, q = 0.f;
        for (int g = 0; g < NGRP; ++g) {
            s += stats[g * 128 + t];
            q += stats[g * 128 + 64 + t];
        }
        float mu = s / (float)NN;
        float var = q / (float)NN - mu * mu;
        float scale = gamma[t] * rsqrtf(var + EPSV);
        sc[t] = scale;
        sc[64 + t] = beta[t] - mu * scale;
    }
    __syncthreads();
    long tot = (long)NN * 64;
    long stride = (long)gridDim.x * blockDim.x;
    for (long i = (long)blockIdx.x * blockDim.x + threadIdx.x; i < tot; i += stride) {
        int cc = (int)(i & 63);
        float v = y[i] * sc[cc] + sc[64 + cc];
        if (HASRES) v += bf2f(resb[i]);
        hb[i] = f2bf(v);
    }
}

extern "C" void kernel_launch(void* const* d_in, const int* in_sizes, int n_in,
                              void* d_out, int out_size, void* d_ws, size_t ws_size,
                              hipStream_t stream) {
    const float* x      = (const float*)d_in[0];
    const int*   ei     = (const int*)d_in[1];
    const int*   et     = (const int*)d_in[2];
    const float* comp1  = (const float*)d_in[3];
    const float* bases1 = (const float*)d_in[4];
    const float* root1  = (const float*)d_in[5];
    const float* bias1  = (const float*)d_in[6];
    const float* comp2  = (const float*)d_in[7];
    const float* bases2 = (const float*)d_in[8];
    const float* root2  = (const float*)d_in[9];
    const float* bias2  = (const float*)d_in[10];
    const float* comp3  = (const float*)d_in[11];
    const float* bases3 = (const float*)d_in[12];
    const float* root3  = (const float*)d_in[13];
    const float* bias3  = (const float*)d_in[14];
    const float* gamma1 = (const float*)d_in[15];
    const float* beta1  = (const float*)d_in[16];
    const float* gamma2 = (const float*)d_in[17];
    const float* beta2  = (const float*)d_in[18];
    float* out = (float*)d_out;

    float* ws = (float*)d_ws;
    size_t off = 0;
    bfu* Wp1 = (bfu*)(ws + off); off += 18432;                // 36864 bf16
    bfu* Wp2 = (bfu*)(ws + off); off += 18432;
    bfu* Wp3 = (bfu*)(ws + off); off += 9216;                 // 18432 bf16
    float* cnt    = ws + off; off += (size_t)NN * RR;         // -- zero region start
    int*   fill   = (int*)(ws + off); off += NN;
    float* stats1 = ws + off; off += NGRP * 128;
    float* stats2 = ws + off; off += NGRP * 128;              // -- zero region end
    float* y  = ws + off; off += (size_t)NN * 64;
    bfu* xb   = (bfu*)(ws + off); off += (size_t)NN * 32;
    bfu* h1b  = (bfu*)(ws + off); off += (size_t)NN * 32;
    bfu* hb   = (bfu*)(ws + off); off += (size_t)NN * 32;
    int* offs = (int*)(ws + off); off += NN + 4;
    int* bsum = (int*)(ws + off); off += 256;
    unsigned* esrt = (unsigned*)(ws + off); off += NE;

    // ---- once: prep (W pack + bf16 cvt + zeros), counts, CSR ----
    prep<<<dim3(2048), dim3(256), 0, stream>>>(comp1, bases1, root1, Wp1,
                                               comp2, bases2, root2, Wp2,
                                               comp3, bases3, root3, Wp3,
                                               x, xb, cnt);
    edge_count<<<dim3(2048), dim3(256), 0, stream>>>(ei, et, cnt);
    scan1<<<dim3(SCAN_B), dim3(256), 0, stream>>>(cnt, offs, bsum);
    scan2<<<dim3(1), dim3(64), 0, stream>>>(bsum, offs);
    scan3<<<dim3(SCAN_B), dim3(256), 0, stream>>>(offs, bsum);
    place<<<dim3(2048), dim3(256), 0, stream>>>(ei, et, offs, fill, esrt);

    // ---- layer 1 ----
    agg_gemm<64, true, true><<<dim3(NN / 16), dim3(256), 0, stream>>>(offs, esrt, cnt, xb, Wp1, bias1, y, stats1);
    bn_apply<false><<<dim3(256), dim3(256), 0, stream>>>(y, stats1, gamma1, beta1, nullptr, h1b);

    // ---- layer 2 ----
    agg_gemm<64, true, true><<<dim3(NN / 16), dim3(256), 0, stream>>>(offs, esrt, cnt, h1b, Wp2, bias2, y, stats2);
    bn_apply<true><<<dim3(256), dim3(256), 0, stream>>>(y, stats2, gamma2, beta2, h1b, hb);

    // ---- layer 3 (output) ----
    agg_gemm<32, false, false><<<dim3(NN / 16), dim3(256), 0, stream>>>(offs, esrt, cnt, hb, Wp3, bias3, out, nullptr);
}